// Round 1
// baseline (2266.403 us; speedup 1.0000x reference)
//
#include <hip/hip_runtime.h>
#include <math.h>

#define N_NODES 100000
#define N_EDGES 1600000

// ---------------- degree / dinv ----------------

__global__ void deg_init_kernel(float* deg) {
    int i = blockIdx.x * blockDim.x + threadIdx.x;
    if (i < N_NODES) deg[i] = 1.0f;  // self-loop
}

__global__ void deg_count_kernel(const int* __restrict__ dst, float* deg) {
    int e = blockIdx.x * blockDim.x + threadIdx.x;
    if (e < N_EDGES) atomicAdd(&deg[dst[e]], 1.0f);
}

__global__ void dinv_kernel(float* deg) {
    int i = blockIdx.x * blockDim.x + threadIdx.x;
    if (i < N_NODES) deg[i] = rsqrtf(deg[i]);  // deg >= 1 always
}

// ---------------- aggregation ----------------
// init agg with self-loop contribution (+ optional bias)
template<int C>
__global__ void agg_self_kernel(const float* __restrict__ h,
                                const float* __restrict__ dinv,
                                const float* __restrict__ bias,
                                float* __restrict__ agg) {
    long idx = (long)blockIdx.x * blockDim.x + threadIdx.x;
    if (idx >= (long)N_NODES * C) return;
    int node = (int)(idx >> __builtin_ctz(C));
    int c = (int)(idx & (C - 1));
    float d = dinv[node];
    float v = d * d * h[idx];
    if (bias) v += bias[c];
    agg[idx] = v;
}

// one thread per (edge, channel): coalesced gather + coalesced atomics
template<int C>
__global__ void agg_edges_kernel(const float* __restrict__ h,
                                 const float* __restrict__ dinv,
                                 const int* __restrict__ src,
                                 const int* __restrict__ dst,
                                 float* agg) {
    long idx = (long)blockIdx.x * blockDim.x + threadIdx.x;
    if (idx >= (long)N_EDGES * C) return;
    int e = (int)(idx >> __builtin_ctz(C));
    int c = (int)(idx & (C - 1));
    int s = src[e], d = dst[e];
    float n = dinv[s] * dinv[d];
    atomicAdd(&agg[(long)d * C + c], h[(long)s * C + c] * n);
}

// ---------------- fp32 tiled GEMM (+bias +relu options) ----------------
// C[N,M] = A[N,K] @ B[K,M]; 64x64 tile, BK=16, 256 threads, 4x4 per thread
template<bool RELU, bool BIAS>
__global__ __launch_bounds__(256) void gemm_kernel(
        const float* __restrict__ A, const float* __restrict__ B,
        const float* __restrict__ bias, float* __restrict__ C,
        int N, int K, int M) {
    __shared__ float As[16][65];
    __shared__ float Bs[16][65];
    int tid = threadIdx.x;
    int row0 = blockIdx.x * 64;
    int col0 = blockIdx.y * 64;
    int tr = tid / 16;  // 0..15
    int tc = tid % 16;  // 0..15
    float acc[4][4] = {};

    for (int k0 = 0; k0 < K; k0 += 16) {
        // A tile: 64 rows x 16 k -> As[k][row]
        for (int i = tid; i < 64 * 16; i += 256) {
            int r = i / 16, k = i % 16;
            int gr = row0 + r;
            As[k][r] = (gr < N) ? A[(long)gr * K + k0 + k] : 0.0f;
        }
        // B tile: 16 k x 64 cols
        for (int i = tid; i < 16 * 64; i += 256) {
            int k = i / 64, c = i % 64;
            Bs[k][c] = B[(long)(k0 + k) * M + col0 + c];
        }
        __syncthreads();
#pragma unroll
        for (int k = 0; k < 16; ++k) {
            float a[4], b[4];
#pragma unroll
            for (int i = 0; i < 4; ++i) a[i] = As[k][tr * 4 + i];
#pragma unroll
            for (int j = 0; j < 4; ++j) b[j] = Bs[k][tc * 4 + j];
#pragma unroll
            for (int i = 0; i < 4; ++i)
#pragma unroll
                for (int j = 0; j < 4; ++j) acc[i][j] += a[i] * b[j];
        }
        __syncthreads();
    }

    for (int i = 0; i < 4; ++i) {
        int gr = row0 + tr * 4 + i;
        if (gr >= N) continue;
        for (int j = 0; j < 4; ++j) {
            int gc = col0 + tc * 4 + j;
            float v = acc[i][j];
            if (BIAS) v += bias[gc];
            if (RELU) v = fmaxf(v, 0.0f);
            C[(long)gr * M + gc] = v;
        }
    }
}

// ---------------- elementwise relu ----------------
__global__ void relu_kernel(float* p, long n4) {
    long i = (long)blockIdx.x * blockDim.x + threadIdx.x;
    if (i >= n4) return;
    float4 v = ((float4*)p)[i];
    v.x = fmaxf(v.x, 0.f); v.y = fmaxf(v.y, 0.f);
    v.z = fmaxf(v.z, 0.f); v.w = fmaxf(v.w, 0.f);
    ((float4*)p)[i] = v;
}

// ---------------- fused relu + log_softmax over 64 channels ----------------
// one 64-lane wave per row, in-place
__global__ void relu_logsoftmax64_kernel(float* out) {
    long gtid = (long)blockIdx.x * blockDim.x + threadIdx.x;
    int row = (int)(gtid >> 6);
    int lane = (int)(gtid & 63);
    if (row >= N_NODES) return;
    float v = out[(long)row * 64 + lane];
    v = fmaxf(v, 0.0f);
    float m = v;
#pragma unroll
    for (int o = 32; o > 0; o >>= 1) m = fmaxf(m, __shfl_xor(m, o));
    float e = expf(v - m);
    float s = e;
#pragma unroll
    for (int o = 32; o > 0; o >>= 1) s += __shfl_xor(s, o);
    out[(long)row * 64 + lane] = v - m - logf(s);
}

// ---------------- launch ----------------

extern "C" void kernel_launch(void* const* d_in, const int* in_sizes, int n_in,
                              void* d_out, int out_size, void* d_ws, size_t ws_size,
                              hipStream_t stream) {
    const float* x  = (const float*)d_in[0];
    const int* edge = (const int*)d_in[1];      // [2][N_EDGES] int32
    const float* W1 = (const float*)d_in[2];
    const float* b1 = (const float*)d_in[3];
    const float* W2 = (const float*)d_in[4];
    const float* b2 = (const float*)d_in[5];
    const float* W3 = (const float*)d_in[6];
    const float* b3 = (const float*)d_in[7];
    float* out = (float*)d_out;

    const int* src = edge;
    const int* dst = edge + N_EDGES;

    float* ws   = (float*)d_ws;
    float* dinv = ws;                       // N floats (doubles as deg)
    float* bufA = ws + 131072;              // N*256 floats
    float* bufB = bufA + (long)N_NODES * 256;  // N*128 floats

    const int BT = 256;

    // --- degrees ---
    deg_init_kernel<<<(N_NODES + BT - 1) / BT, BT, 0, stream>>>(dinv);
    deg_count_kernel<<<(N_EDGES + BT - 1) / BT, BT, 0, stream>>>(dst, dinv);
    dinv_kernel<<<(N_NODES + BT - 1) / BT, BT, 0, stream>>>(dinv);

    // --- layer 1: aggregate x (128 ch) first, then GEMM 128->256 +b1 +relu ---
    {
        long n = (long)N_NODES * 128;
        agg_self_kernel<128><<<(n + BT - 1) / BT, BT, 0, stream>>>(x, dinv, nullptr, bufB);
        long ne = (long)N_EDGES * 128;
        agg_edges_kernel<128><<<(ne + BT - 1) / BT, BT, 0, stream>>>(x, dinv, src, dst, bufB);
        dim3 g((N_NODES + 63) / 64, 256 / 64);
        gemm_kernel<true, true><<<g, BT, 0, stream>>>(bufB, W1, b1, bufA, N_NODES, 128, 256);
    }

    // --- layer 2: GEMM 256->128 first, then aggregate (128 ch) +b2 +relu ---
    {
        dim3 g((N_NODES + 63) / 64, 128 / 64);
        gemm_kernel<false, false><<<g, BT, 0, stream>>>(bufA, W2, nullptr, bufB, N_NODES, 256, 128);
        long n = (long)N_NODES * 128;
        agg_self_kernel<128><<<(n + BT - 1) / BT, BT, 0, stream>>>(bufB, dinv, b2, bufA);
        long ne = (long)N_EDGES * 128;
        agg_edges_kernel<128><<<(ne + BT - 1) / BT, BT, 0, stream>>>(bufB, dinv, src, dst, bufA);
        relu_kernel<<<(int)((n / 4 + BT - 1) / BT), BT, 0, stream>>>(bufA, n / 4);
    }

    // --- layer 3: GEMM 128->64 first, then aggregate (64 ch) +b3, relu+log_softmax ---
    {
        dim3 g((N_NODES + 63) / 64, 64 / 64);
        gemm_kernel<false, false><<<g, BT, 0, stream>>>(bufA, W3, nullptr, bufB, N_NODES, 128, 64);
        long n = (long)N_NODES * 64;
        agg_self_kernel<64><<<(n + BT - 1) / BT, BT, 0, stream>>>(bufB, dinv, b3, out);
        long ne = (long)N_EDGES * 64;
        agg_edges_kernel<64><<<(ne + BT - 1) / BT, BT, 0, stream>>>(bufB, dinv, src, dst, out);
        relu_logsoftmax64_kernel<<<(int)((n + BT - 1) / BT), BT, 0, stream>>>(out);
    }

    (void)in_sizes; (void)n_in; (void)out_size; (void)ws_size;
}

// Round 2
// 848.301 us; speedup vs baseline: 2.6717x; 2.6717x over previous
//
#include <hip/hip_runtime.h>
#include <math.h>

#define N_NODES 100000
#define N_EDGES 1600000
#define NBLK_SCAN ((N_NODES + 255) / 256)   // 391

// ---------------- degree ----------------

__global__ void deg_count_kernel(const int* __restrict__ dst, int* deg) {
    int e = blockIdx.x * blockDim.x + threadIdx.x;
    if (e < N_EDGES) atomicAdd(&deg[dst[e]], 1);
}

__global__ void dinv_kernel(const int* __restrict__ deg, float* dinv) {
    int i = blockIdx.x * blockDim.x + threadIdx.x;
    if (i < N_NODES) dinv[i] = rsqrtf(1.0f + (float)deg[i]);  // +1 self-loop
}

// ---------------- exclusive scan (3-phase) ----------------

__global__ void scan1_kernel(const int* __restrict__ deg, int* __restrict__ ex,
                             int* __restrict__ bsum) {
    __shared__ int tmp[256];
    int i = blockIdx.x * 256 + threadIdx.x;
    int v = (i < N_NODES) ? deg[i] : 0;
    tmp[threadIdx.x] = v;
    __syncthreads();
    for (int off = 1; off < 256; off <<= 1) {
        int t = (threadIdx.x >= off) ? tmp[threadIdx.x - off] : 0;
        __syncthreads();
        tmp[threadIdx.x] += t;
        __syncthreads();
    }
    if (i < N_NODES) ex[i] = tmp[threadIdx.x] - v;  // exclusive
    if (threadIdx.x == 255) bsum[blockIdx.x] = tmp[255];
}

__global__ void scan2_kernel(int* bsum) {  // single block of 512
    __shared__ int tmp[512];
    int i = threadIdx.x;
    int v = (i < NBLK_SCAN) ? bsum[i] : 0;
    tmp[i] = v;
    __syncthreads();
    for (int off = 1; off < 512; off <<= 1) {
        int t = (i >= off) ? tmp[i - off] : 0;
        __syncthreads();
        tmp[i] += t;
        __syncthreads();
    }
    if (i < NBLK_SCAN) bsum[i] = tmp[i] - v;  // exclusive
}

__global__ void scan3_kernel(int* rowptr, const int* __restrict__ bsum) {
    int i = blockIdx.x * 256 + threadIdx.x;
    if (i < N_NODES) rowptr[i] += bsum[blockIdx.x];
}

// ---------------- edge scatter (counting sort by dst) ----------------

__global__ void scatter_kernel(const int* __restrict__ src, const int* __restrict__ dst,
                               const float* __restrict__ dinv, const int* __restrict__ rowptr,
                               int* cursor, int* __restrict__ ssrc, float* __restrict__ sw) {
    int e = blockIdx.x * blockDim.x + threadIdx.x;
    if (e >= N_EDGES) return;
    int d = dst[e], s = src[e];
    int pos = rowptr[d] + atomicAdd(&cursor[d], 1);
    ssrc[pos] = s;
    sw[pos] = dinv[s];
}

// ---------------- CSR gather aggregation ----------------
// one 64-lane wave per dst node; lane owns C/64 channels
// out[n] = dinv[n] * ( dinv[n]*h[n] + sum_edges dinv[s]*h[s] ) (+bias)(relu)(logsm)
template<int C, bool BIAS, bool RELU, bool LOGSM>
__global__ void agg_csr_kernel(const float* __restrict__ h, const float* __restrict__ dinv,
                               const int* __restrict__ rowptr, const int* __restrict__ deg,
                               const int* __restrict__ ssrc, const float* __restrict__ sw,
                               const float* __restrict__ bias, float* __restrict__ out) {
    constexpr int V = C / 64;  // 2 for C=128, 1 for C=64
    int gw = (int)((blockIdx.x * (long)blockDim.x + threadIdx.x) >> 6);
    int lane = threadIdx.x & 63;
    if (gw >= N_NODES) return;

    float di = dinv[gw];
    int st = rowptr[gw];
    int cnt = deg[gw];
    float a0, a1 = 0.0f;
    if constexpr (V == 2) {
        float2 hv = *(const float2*)(h + (long)gw * C + lane * 2);
        a0 = di * hv.x; a1 = di * hv.y;
    } else {
        a0 = di * h[(long)gw * C + lane];
    }

    int k = 0;
    for (; k + 4 <= cnt; k += 4) {
        int s0 = ssrc[st + k], s1 = ssrc[st + k + 1];
        int s2 = ssrc[st + k + 2], s3 = ssrc[st + k + 3];
        float w0 = sw[st + k], w1 = sw[st + k + 1];
        float w2 = sw[st + k + 2], w3 = sw[st + k + 3];
        if constexpr (V == 2) {
            float2 v0 = *(const float2*)(h + (long)s0 * C + lane * 2);
            float2 v1 = *(const float2*)(h + (long)s1 * C + lane * 2);
            float2 v2 = *(const float2*)(h + (long)s2 * C + lane * 2);
            float2 v3 = *(const float2*)(h + (long)s3 * C + lane * 2);
            a0 += w0 * v0.x; a1 += w0 * v0.y;
            a0 += w1 * v1.x; a1 += w1 * v1.y;
            a0 += w2 * v2.x; a1 += w2 * v2.y;
            a0 += w3 * v3.x; a1 += w3 * v3.y;
        } else {
            a0 += w0 * h[(long)s0 * C + lane];
            a0 += w1 * h[(long)s1 * C + lane];
            a0 += w2 * h[(long)s2 * C + lane];
            a0 += w3 * h[(long)s3 * C + lane];
        }
    }
    for (; k < cnt; ++k) {
        int s = ssrc[st + k];
        float w = sw[st + k];
        if constexpr (V == 2) {
            float2 v = *(const float2*)(h + (long)s * C + lane * 2);
            a0 += w * v.x; a1 += w * v.y;
        } else {
            a0 += w * h[(long)s * C + lane];
        }
    }

    a0 *= di; a1 *= di;
    if constexpr (BIAS) {
        if constexpr (V == 2) { a0 += bias[lane * 2]; a1 += bias[lane * 2 + 1]; }
        else a0 += bias[lane];
    }
    if constexpr (RELU) { a0 = fmaxf(a0, 0.0f); a1 = fmaxf(a1, 0.0f); }
    if constexpr (LOGSM) {  // V==1 only: full row in the wave
        float m = a0;
#pragma unroll
        for (int o = 32; o > 0; o >>= 1) m = fmaxf(m, __shfl_xor(m, o));
        float e = expf(a0 - m), s = e;
#pragma unroll
        for (int o = 32; o > 0; o >>= 1) s += __shfl_xor(s, o);
        a0 = a0 - m - logf(s);
    }
    if constexpr (V == 2) {
        float2 r; r.x = a0; r.y = a1;
        *(float2*)(out + (long)gw * C + lane * 2) = r;
    } else {
        out[(long)gw * C + lane] = a0;
    }
}

// ---------------- fp32 tiled GEMM (+bias +relu options) ----------------
template<bool RELU, bool BIAS>
__global__ __launch_bounds__(256) void gemm_kernel(
        const float* __restrict__ A, const float* __restrict__ B,
        const float* __restrict__ bias, float* __restrict__ C,
        int N, int K, int M) {
    __shared__ float As[16][65];
    __shared__ float Bs[16][65];
    int tid = threadIdx.x;
    int row0 = blockIdx.x * 64;
    int col0 = blockIdx.y * 64;
    int tr = tid / 16;
    int tc = tid % 16;
    float acc[4][4] = {};

    for (int k0 = 0; k0 < K; k0 += 16) {
        for (int i = tid; i < 64 * 16; i += 256) {
            int r = i / 16, k = i % 16;
            int gr = row0 + r;
            As[k][r] = (gr < N) ? A[(long)gr * K + k0 + k] : 0.0f;
        }
        for (int i = tid; i < 16 * 64; i += 256) {
            int k = i / 64, c = i % 64;
            Bs[k][c] = B[(long)(k0 + k) * M + col0 + c];
        }
        __syncthreads();
#pragma unroll
        for (int k = 0; k < 16; ++k) {
            float a[4], b[4];
#pragma unroll
            for (int i = 0; i < 4; ++i) a[i] = As[k][tr * 4 + i];
#pragma unroll
            for (int j = 0; j < 4; ++j) b[j] = Bs[k][tc * 4 + j];
#pragma unroll
            for (int i = 0; i < 4; ++i)
#pragma unroll
                for (int j = 0; j < 4; ++j) acc[i][j] += a[i] * b[j];
        }
        __syncthreads();
    }

    for (int i = 0; i < 4; ++i) {
        int gr = row0 + tr * 4 + i;
        if (gr >= N) continue;
        for (int j = 0; j < 4; ++j) {
            int gc = col0 + tc * 4 + j;
            float v = acc[i][j];
            if (BIAS) v += bias[gc];
            if (RELU) v = fmaxf(v, 0.0f);
            C[(long)gr * M + gc] = v;
        }
    }
}

// ---------------- launch ----------------

extern "C" void kernel_launch(void* const* d_in, const int* in_sizes, int n_in,
                              void* d_out, int out_size, void* d_ws, size_t ws_size,
                              hipStream_t stream) {
    const float* x  = (const float*)d_in[0];
    const int* edge = (const int*)d_in[1];
    const float* W1 = (const float*)d_in[2];
    const float* b1 = (const float*)d_in[3];
    const float* W2 = (const float*)d_in[4];
    const float* b2 = (const float*)d_in[5];
    const float* W3 = (const float*)d_in[6];
    const float* b3 = (const float*)d_in[7];
    float* out = (float*)d_out;

    const int* src = edge;
    const int* dst = edge + N_EDGES;

    // workspace layout (element offsets, all even -> 8B aligned)
    float* ws    = (float*)d_ws;
    float* dinv  = ws;                                   // [0,      100000)
    int*   degi  = (int*)(ws + 100000);                  // [100000, 200000)
    int*   rowp  = (int*)(ws + 200000);                  // [200000, 300000)
    int*   curs  = (int*)(ws + 300000);                  // [300000, 400000)
    int*   bsum  = (int*)(ws + 400000);                  // [400000, 401024)
    int*   ssrc  = (int*)(ws + 401024);                  // [401024, 2001024)
    float* sw    = ws + 2001024;                         // [2001024,3601024)
    float* bufA  = ws + 3601024;                         // N*256
    float* bufB  = bufA + (long)N_NODES * 256;           // N*128

    const int BT = 256;
    int gN = (N_NODES + BT - 1) / BT;
    int gE = (N_EDGES + BT - 1) / BT;
    int gAgg = (int)(((long)N_NODES * 64 + BT - 1) / BT);  // one wave per node

    // --- degree + dinv ---
    hipMemsetAsync(degi, 0, N_NODES * sizeof(int), stream);
    deg_count_kernel<<<gE, BT, 0, stream>>>(dst, degi);
    dinv_kernel<<<gN, BT, 0, stream>>>(degi, dinv);

    // --- CSR build: exclusive scan + scatter ---
    scan1_kernel<<<NBLK_SCAN, 256, 0, stream>>>(degi, rowp, bsum);
    scan2_kernel<<<1, 512, 0, stream>>>(bsum);
    scan3_kernel<<<NBLK_SCAN, 256, 0, stream>>>(rowp, bsum);
    hipMemsetAsync(curs, 0, N_NODES * sizeof(int), stream);
    scatter_kernel<<<gE, BT, 0, stream>>>(src, dst, dinv, rowp, curs, ssrc, sw);

    // --- layer 1: aggregate x (128 ch), then GEMM 128->256 +b1 +relu ---
    agg_csr_kernel<128, false, false, false><<<gAgg, BT, 0, stream>>>(
        x, dinv, rowp, degi, ssrc, sw, nullptr, bufB);
    {
        dim3 g((N_NODES + 63) / 64, 256 / 64);
        gemm_kernel<true, true><<<g, BT, 0, stream>>>(bufB, W1, b1, bufA, N_NODES, 128, 256);
    }

    // --- layer 2: GEMM 256->128, then aggregate +b2 +relu ---
    {
        dim3 g((N_NODES + 63) / 64, 128 / 64);
        gemm_kernel<false, false><<<g, BT, 0, stream>>>(bufA, W2, nullptr, bufB, N_NODES, 256, 128);
    }
    agg_csr_kernel<128, true, true, false><<<gAgg, BT, 0, stream>>>(
        bufB, dinv, rowp, degi, ssrc, sw, b2, bufA);

    // --- layer 3: GEMM 128->64, then aggregate +b3 +relu +log_softmax ---
    {
        dim3 g((N_NODES + 63) / 64, 64 / 64);
        gemm_kernel<false, false><<<g, BT, 0, stream>>>(bufA, W3, nullptr, bufB, N_NODES, 128, 64);
    }
    agg_csr_kernel<64, true, true, true><<<gAgg, BT, 0, stream>>>(
        bufB, dinv, rowp, degi, ssrc, sw, b3, out);

    (void)in_sizes; (void)n_in; (void)out_size; (void)ws_size;
}

// Round 3
// 509.188 us; speedup vs baseline: 4.4510x; 1.6660x over previous
//
#include <hip/hip_runtime.h>
#include <math.h>

#define N_NODES 100000
#define N_EDGES 1600000
#define NBLK_SCAN ((N_NODES + 255) / 256)   // 391
#define NPAD 100064                          // 64-row padded for GEMM staging

typedef __attribute__((ext_vector_type(8))) short bf16x8;
typedef __attribute__((ext_vector_type(4))) float f32x4;

__device__ __forceinline__ unsigned short f2bf(float f) {
    unsigned int u = __builtin_bit_cast(unsigned int, f);
    u += 0x7fffu + ((u >> 16) & 1u);          // RNE
    return (unsigned short)(u >> 16);
}
__device__ __forceinline__ float bflo2f(unsigned int u) {   // low 16 bits = bf16
    return __builtin_bit_cast(float, u << 16);
}
__device__ __forceinline__ float bfhi2f(unsigned int u) {   // high 16 bits = bf16
    return __builtin_bit_cast(float, u & 0xffff0000u);
}

// ---------------- degree ----------------

__global__ void deg_count_kernel(const int* __restrict__ dst, int* deg) {
    int e = blockIdx.x * blockDim.x + threadIdx.x;
    if (e < N_EDGES) atomicAdd(&deg[dst[e]], 1);
}

__global__ void dinv_kernel(const int* __restrict__ deg, float* dinv) {
    int i = blockIdx.x * blockDim.x + threadIdx.x;
    if (i < N_NODES) dinv[i] = rsqrtf(1.0f + (float)deg[i]);  // +1 self-loop
}

// ---------------- exclusive scan (3-phase) ----------------

__global__ void scan1_kernel(const int* __restrict__ deg, int* __restrict__ ex,
                             int* __restrict__ bsum) {
    __shared__ int tmp[256];
    int i = blockIdx.x * 256 + threadIdx.x;
    int v = (i < N_NODES) ? deg[i] : 0;
    tmp[threadIdx.x] = v;
    __syncthreads();
    for (int off = 1; off < 256; off <<= 1) {
        int t = (threadIdx.x >= off) ? tmp[threadIdx.x - off] : 0;
        __syncthreads();
        tmp[threadIdx.x] += t;
        __syncthreads();
    }
    if (i < N_NODES) ex[i] = tmp[threadIdx.x] - v;
    if (threadIdx.x == 255) bsum[blockIdx.x] = tmp[255];
}

__global__ void scan2_kernel(int* bsum) {
    __shared__ int tmp[512];
    int i = threadIdx.x;
    int v = (i < NBLK_SCAN) ? bsum[i] : 0;
    tmp[i] = v;
    __syncthreads();
    for (int off = 1; off < 512; off <<= 1) {
        int t = (i >= off) ? tmp[i - off] : 0;
        __syncthreads();
        tmp[i] += t;
        __syncthreads();
    }
    if (i < NBLK_SCAN) bsum[i] = tmp[i] - v;
}

__global__ void scan3_kernel(int* rowptr, const int* __restrict__ bsum) {
    int i = blockIdx.x * 256 + threadIdx.x;
    if (i < N_NODES) rowptr[i] += bsum[blockIdx.x];
}

// ---------------- edge scatter (counting sort by dst) ----------------

__global__ void scatter_kernel(const int* __restrict__ src, const int* __restrict__ dst,
                               const float* __restrict__ dinv, const int* __restrict__ rowptr,
                               int* cursor, int* __restrict__ ssrc, float* __restrict__ sw) {
    int e = blockIdx.x * blockDim.x + threadIdx.x;
    if (e >= N_EDGES) return;
    int d = dst[e], s = src[e];
    int pos = rowptr[d] + atomicAdd(&cursor[d], 1);
    ssrc[pos] = s;
    sw[pos] = dinv[s];
}

// ---------------- conversions ----------------

__global__ void cvt_x_kernel(const float* __restrict__ x, unsigned short* __restrict__ xb) {
    long i = (long)blockIdx.x * blockDim.x + threadIdx.x;   // over n/4
    if (i >= (long)N_NODES * 128 / 4) return;
    float4 v = ((const float4*)x)[i];
    ushort4 o;
    o.x = f2bf(v.x); o.y = f2bf(v.y); o.z = f2bf(v.z); o.w = f2bf(v.w);
    ((ushort4*)xb)[i] = o;
}

// Wt[m][k] = bf16(W[k][m])
__global__ void cvt_w_kernel(const float* __restrict__ W, unsigned short* __restrict__ Wt,
                             int K, int M) {
    int i = blockIdx.x * blockDim.x + threadIdx.x;
    if (i >= K * M) return;
    int k = i / M, m = i % M;
    Wt[(long)m * K + k] = f2bf(W[i]);
}

// ---------------- CSR gather aggregation (bf16 in, bf16/f32 out) ----------------
// one 64-lane wave per dst node; lane owns C/64 channels
template<int C, bool BIAS, bool RELU, bool LOGSM, bool OUTF32>
__global__ void agg_csr_kernel(const unsigned short* __restrict__ h,
                               const float* __restrict__ dinv,
                               const int* __restrict__ rowptr, const int* __restrict__ deg,
                               const int* __restrict__ ssrc, const float* __restrict__ sw,
                               const float* __restrict__ bias, void* __restrict__ outv) {
    constexpr int V = C / 64;  // 2 for C=128, 1 for C=64
    int gw = (int)((blockIdx.x * (long)blockDim.x + threadIdx.x) >> 6);
    int lane = threadIdx.x & 63;
    if (gw >= N_NODES) return;

    float di = dinv[gw];
    int st = rowptr[gw];
    int cnt = deg[gw];
    float a0, a1 = 0.0f;
    if constexpr (V == 2) {
        unsigned int u = ((const unsigned int*)(h + (long)gw * C))[lane];
        a0 = di * bflo2f(u); a1 = di * bfhi2f(u);
    } else {
        a0 = di * bflo2f(h[(long)gw * C + lane]);
    }

    int k = 0;
    for (; k + 4 <= cnt; k += 4) {
        int s0 = ssrc[st + k], s1 = ssrc[st + k + 1];
        int s2 = ssrc[st + k + 2], s3 = ssrc[st + k + 3];
        float w0 = sw[st + k], w1 = sw[st + k + 1];
        float w2 = sw[st + k + 2], w3 = sw[st + k + 3];
        if constexpr (V == 2) {
            unsigned int u0 = ((const unsigned int*)(h + (long)s0 * C))[lane];
            unsigned int u1 = ((const unsigned int*)(h + (long)s1 * C))[lane];
            unsigned int u2 = ((const unsigned int*)(h + (long)s2 * C))[lane];
            unsigned int u3 = ((const unsigned int*)(h + (long)s3 * C))[lane];
            a0 += w0 * bflo2f(u0); a1 += w0 * bfhi2f(u0);
            a0 += w1 * bflo2f(u1); a1 += w1 * bfhi2f(u1);
            a0 += w2 * bflo2f(u2); a1 += w2 * bfhi2f(u2);
            a0 += w3 * bflo2f(u3); a1 += w3 * bfhi2f(u3);
        } else {
            a0 += w0 * bflo2f(h[(long)s0 * C + lane]);
            a0 += w1 * bflo2f(h[(long)s1 * C + lane]);
            a0 += w2 * bflo2f(h[(long)s2 * C + lane]);
            a0 += w3 * bflo2f(h[(long)s3 * C + lane]);
        }
    }
    for (; k < cnt; ++k) {
        int s = ssrc[st + k];
        float w = sw[st + k];
        if constexpr (V == 2) {
            unsigned int u = ((const unsigned int*)(h + (long)s * C))[lane];
            a0 += w * bflo2f(u); a1 += w * bfhi2f(u);
        } else {
            a0 += w * bflo2f(h[(long)s * C + lane]);
        }
    }

    a0 *= di; a1 *= di;
    if constexpr (BIAS) {
        if constexpr (V == 2) { a0 += bias[lane * 2]; a1 += bias[lane * 2 + 1]; }
        else a0 += bias[lane];
    }
    if constexpr (RELU) { a0 = fmaxf(a0, 0.0f); a1 = fmaxf(a1, 0.0f); }
    if constexpr (LOGSM) {  // V==1 only
        float m = a0;
#pragma unroll
        for (int o = 32; o > 0; o >>= 1) m = fmaxf(m, __shfl_xor(m, o));
        float e = expf(a0 - m), s = e;
#pragma unroll
        for (int o = 32; o > 0; o >>= 1) s += __shfl_xor(s, o);
        a0 = a0 - m - logf(s);
    }
    if constexpr (OUTF32) {
        float* out = (float*)outv;
        if constexpr (V == 2) {
            float2 r; r.x = a0; r.y = a1;
            *(float2*)(out + (long)gw * C + lane * 2) = r;
        } else {
            out[(long)gw * C + lane] = a0;
        }
    } else {
        unsigned short* out = (unsigned short*)outv;
        if constexpr (V == 2) {
            unsigned int up = (unsigned int)f2bf(a0) | ((unsigned int)f2bf(a1) << 16);
            ((unsigned int*)(out + (long)gw * C))[lane] = up;
        } else {
            out[(long)gw * C + lane] = f2bf(a0);
        }
    }
}

// ---------------- bf16 MFMA GEMM ----------------
// C[N,M](bf16) = A[N,K](bf16) @ Wt[M,K]^T (+bias)(relu)
// 64x64 block tile, 4 waves 2x2, each wave 32x32 via mfma_f32_16x16x32_bf16.
// Whole-K panels staged once to LDS with XOR row-swizzle (write & read identical).
template<int K, int M, bool BIAS, bool RELU>
__global__ __launch_bounds__(256) void gemm_mfma_kernel(
        const unsigned short* __restrict__ A,   // [NPAD][K]
        const unsigned short* __restrict__ Bt,  // [M][K]
        const float* __restrict__ bias,         // [M]
        unsigned short* __restrict__ Cb,        // [NPAD][M]
        int N) {
    constexpr int KC = K / 8;                    // 16B chunks per row
    __shared__ unsigned short As[64 * K];
    __shared__ unsigned short Bs[64 * K];

    int tid = threadIdx.x;
    int row0 = blockIdx.x * 64;
    int col0 = blockIdx.y * 64;

    const unsigned short* Ap = A + (long)row0 * K;
    const unsigned short* Bp = Bt + (long)col0 * K;

    // stage both panels; LDS byte = (c*16) ^ ((row&7)<<4)
    for (int c = tid; c < 64 * KC; c += 256) {
        int r = c / KC;
        unsigned int swz = ((unsigned int)c * 16u) ^ ((unsigned int)(r & 7) << 4);
        bf16x8 va = *(const bf16x8*)(Ap + c * 8);
        bf16x8 vb = *(const bf16x8*)(Bp + c * 8);
        *(bf16x8*)((char*)As + swz) = va;
        *(bf16x8*)((char*)Bs + swz) = vb;
    }
    __syncthreads();

    int lane = tid & 63;
    int wv = tid >> 6;
    int wr = wv >> 1, wc = wv & 1;      // wave tile origin (wr*32, wc*32)
    int lr = lane & 15;
    int kg = lane >> 4;                 // k-group: k = kg*8 + j

    f32x4 acc[2][2] = {};

    for (int k0 = 0; k0 < K; k0 += 32) {
        bf16x8 a[2], b[2];
#pragma unroll
        for (int mi = 0; mi < 2; ++mi) {
            int r = wr * 32 + mi * 16 + lr;
            unsigned int byteo = (unsigned int)((r * K + k0 + kg * 8) * 2);
            byteo ^= (unsigned int)((r & 7) << 4);
            a[mi] = *(const bf16x8*)((const char*)As + byteo);
        }
#pragma unroll
        for (int ni = 0; ni < 2; ++ni) {
            int r = wc * 32 + ni * 16 + lr;
            unsigned int byteo = (unsigned int)((r * K + k0 + kg * 8) * 2);
            byteo ^= (unsigned int)((r & 7) << 4);
            b[ni] = *(const bf16x8*)((const char*)Bs + byteo);
        }
#pragma unroll
        for (int mi = 0; mi < 2; ++mi)
#pragma unroll
            for (int ni = 0; ni < 2; ++ni)
                acc[mi][ni] = __builtin_amdgcn_mfma_f32_16x16x32_bf16(
                    a[mi], b[ni], acc[mi][ni], 0, 0, 0);
    }

    // epilogue: C/D layout col=lane&15, row=(lane>>4)*4+i
#pragma unroll
    for (int mi = 0; mi < 2; ++mi) {
#pragma unroll
        for (int ni = 0; ni < 2; ++ni) {
            int col = col0 + wc * 32 + ni * 16 + lr;
            float bv = BIAS ? bias[col] : 0.0f;
#pragma unroll
            for (int i = 0; i < 4; ++i) {
                int row = row0 + wr * 32 + mi * 16 + kg * 4 + i;
                if (row < N) {
                    float v = acc[mi][ni][i] + bv;
                    if (RELU) v = fmaxf(v, 0.0f);
                    Cb[(long)row * M + col] = f2bf(v);
                }
            }
        }
    }
}

// ---------------- launch ----------------

extern "C" void kernel_launch(void* const* d_in, const int* in_sizes, int n_in,
                              void* d_out, int out_size, void* d_ws, size_t ws_size,
                              hipStream_t stream) {
    const float* x  = (const float*)d_in[0];
    const int* edge = (const int*)d_in[1];
    const float* W1 = (const float*)d_in[2];
    const float* b1 = (const float*)d_in[3];
    const float* W2 = (const float*)d_in[4];
    const float* b2 = (const float*)d_in[5];
    const float* W3 = (const float*)d_in[6];
    const float* b3 = (const float*)d_in[7];
    float* out = (float*)d_out;

    const int* src = edge;
    const int* dst = edge + N_EDGES;

    // workspace: fp32/int CSR region, then bf16 buffers
    float* ws    = (float*)d_ws;
    float* dinv  = ws;                                   // N
    int*   degi  = (int*)(ws + 100000);
    int*   rowp  = (int*)(ws + 200000);
    int*   curs  = (int*)(ws + 300000);
    int*   bsum  = (int*)(ws + 400000);
    int*   ssrc  = (int*)(ws + 401024);                  // E
    float* sw    = ws + 2001024;                         // E
    unsigned short* P1  = (unsigned short*)(ws + 3601024);   // [NPAD][128]
    unsigned short* P2  = P1 + (size_t)NPAD * 128;           // [NPAD][128]
    unsigned short* P3  = P2 + (size_t)NPAD * 128;           // [NPAD][256]
    unsigned short* Wt1 = P3 + (size_t)NPAD * 256;           // [256][128]
    unsigned short* Wt2 = Wt1 + 128 * 256;                   // [128][256]
    unsigned short* Wt3 = Wt2 + 256 * 128;                   // [64][128]

    const int BT = 256;
    int gN = (N_NODES + BT - 1) / BT;
    int gE = (N_EDGES + BT - 1) / BT;
    int gAgg = (int)(((long)N_NODES * 64 + BT - 1) / BT);
    int gRows = (N_NODES + 63) / 64;   // 1563

    // --- degree + dinv + CSR ---
    hipMemsetAsync(degi, 0, N_NODES * sizeof(int), stream);
    deg_count_kernel<<<gE, BT, 0, stream>>>(dst, degi);
    dinv_kernel<<<gN, BT, 0, stream>>>(degi, dinv);
    scan1_kernel<<<NBLK_SCAN, 256, 0, stream>>>(degi, rowp, bsum);
    scan2_kernel<<<1, 512, 0, stream>>>(bsum);
    scan3_kernel<<<NBLK_SCAN, 256, 0, stream>>>(rowp, bsum);
    hipMemsetAsync(curs, 0, N_NODES * sizeof(int), stream);
    scatter_kernel<<<gE, BT, 0, stream>>>(src, dst, dinv, rowp, curs, ssrc, sw);

    // --- conversions ---
    cvt_x_kernel<<<(int)(((long)N_NODES * 128 / 4 + BT - 1) / BT), BT, 0, stream>>>(x, P1);
    cvt_w_kernel<<<(128 * 256 + BT - 1) / BT, BT, 0, stream>>>(W1, Wt1, 128, 256);
    cvt_w_kernel<<<(256 * 128 + BT - 1) / BT, BT, 0, stream>>>(W2, Wt2, 256, 128);
    cvt_w_kernel<<<(128 * 64 + BT - 1) / BT, BT, 0, stream>>>(W3, Wt3, 128, 64);

    // --- layer 1: agg(x) [P1->P2], gemm 128->256 +b1 +relu [P2->P3] ---
    agg_csr_kernel<128, false, false, false, false><<<gAgg, BT, 0, stream>>>(
        P1, dinv, rowp, degi, ssrc, sw, nullptr, P2);
    {
        dim3 g(gRows, 4);
        gemm_mfma_kernel<128, 256, true, true><<<g, BT, 0, stream>>>(P2, Wt1, b1, P3, N_NODES);
    }

    // --- layer 2: gemm 256->128 [P3->P1], agg +b2 +relu [P1->P2] ---
    {
        dim3 g(gRows, 2);
        gemm_mfma_kernel<256, 128, false, false><<<g, BT, 0, stream>>>(P3, Wt2, nullptr, P1, N_NODES);
    }
    agg_csr_kernel<128, true, true, false, false><<<gAgg, BT, 0, stream>>>(
        P1, dinv, rowp, degi, ssrc, sw, b2, P2);

    // --- layer 3: gemm 128->64 [P2->P1], agg +b3 +relu +logsm [P1->out] ---
    {
        dim3 g(gRows, 1);
        gemm_mfma_kernel<128, 64, false, false><<<g, BT, 0, stream>>>(P2, Wt3, nullptr, P1, N_NODES);
    }
    agg_csr_kernel<64, true, true, true, true><<<gAgg, BT, 0, stream>>>(
        P1, dinv, rowp, degi, ssrc, sw, b3, out);

    (void)in_sizes; (void)n_in; (void)out_size; (void)ws_size;
}

// Round 4
// 502.683 us; speedup vs baseline: 4.5086x; 1.0129x over previous
//
#include <hip/hip_runtime.h>
#include <math.h>

#define N_NODES 100000
#define N_EDGES 1600000
#define NBLK_SCAN ((N_NODES + 255) / 256)   // 391
#define NPAD 100064                          // 64-row padded for GEMM staging

typedef __attribute__((ext_vector_type(8))) short bf16x8;
typedef __attribute__((ext_vector_type(4))) float f32x4;

__device__ __forceinline__ unsigned short f2bf(float f) {
    unsigned int u = __builtin_bit_cast(unsigned int, f);
    u += 0x7fffu + ((u >> 16) & 1u);          // RNE
    return (unsigned short)(u >> 16);
}
__device__ __forceinline__ float bflo2f(unsigned int u) {   // low 16 bits = bf16
    return __builtin_bit_cast(float, u << 16);
}
__device__ __forceinline__ float bfhi2f(unsigned int u) {   // high 16 bits = bf16
    return __builtin_bit_cast(float, u & 0xffff0000u);
}

// ---------------- degree ----------------

__global__ void deg_count_kernel(const int* __restrict__ dst, int* deg) {
    int e = blockIdx.x * blockDim.x + threadIdx.x;
    if (e < N_EDGES) atomicAdd(&deg[dst[e]], 1);
}

__global__ void dinv_kernel(const int* __restrict__ deg, float* dinv) {
    int i = blockIdx.x * blockDim.x + threadIdx.x;
    if (i < N_NODES) dinv[i] = rsqrtf(1.0f + (float)deg[i]);  // +1 self-loop
}

// ---------------- exclusive scan (3-phase) ----------------

__global__ void scan1_kernel(const int* __restrict__ deg, int* __restrict__ ex,
                             int* __restrict__ bsum) {
    __shared__ int tmp[256];
    int i = blockIdx.x * 256 + threadIdx.x;
    int v = (i < N_NODES) ? deg[i] : 0;
    tmp[threadIdx.x] = v;
    __syncthreads();
    for (int off = 1; off < 256; off <<= 1) {
        int t = (threadIdx.x >= off) ? tmp[threadIdx.x - off] : 0;
        __syncthreads();
        tmp[threadIdx.x] += t;
        __syncthreads();
    }
    if (i < N_NODES) ex[i] = tmp[threadIdx.x] - v;
    if (threadIdx.x == 255) bsum[blockIdx.x] = tmp[255];
}

__global__ void scan2_kernel(int* bsum) {
    __shared__ int tmp[512];
    int i = threadIdx.x;
    int v = (i < NBLK_SCAN) ? bsum[i] : 0;
    tmp[i] = v;
    __syncthreads();
    for (int off = 1; off < 512; off <<= 1) {
        int t = (i >= off) ? tmp[i - off] : 0;
        __syncthreads();
        tmp[i] += t;
        __syncthreads();
    }
    if (i < NBLK_SCAN) bsum[i] = tmp[i] - v;
}

__global__ void scan3_kernel(int* rowptr, const int* __restrict__ bsum) {
    int i = blockIdx.x * 256 + threadIdx.x;
    if (i < N_NODES) rowptr[i] += bsum[blockIdx.x];
}

__global__ void copy_rowp_kernel(const int* __restrict__ rowp, int* __restrict__ curs) {
    int i = blockIdx.x * 256 + threadIdx.x;
    if (i < N_NODES) curs[i] = rowp[i];
}

// ---------------- edge scatter (counting sort by dst, AoS 8B record) ----------------

__global__ void scatter_kernel(const int* __restrict__ src, const int* __restrict__ dst,
                               const float* __restrict__ dinv,
                               int* curs, int2* __restrict__ sedge) {
    int e = blockIdx.x * blockDim.x + threadIdx.x;
    if (e >= N_EDGES) return;
    int d = dst[e], s = src[e];
    int pos = atomicAdd(&curs[d], 1);   // curs pre-initialized to rowptr
    int2 rec;
    rec.x = s;
    rec.y = __float_as_int(dinv[s]);
    sedge[pos] = rec;
}

// ---------------- conversions ----------------

__global__ void cvt_x_kernel(const float* __restrict__ x, unsigned short* __restrict__ xb) {
    long i = (long)blockIdx.x * blockDim.x + threadIdx.x;   // over n/4
    if (i >= (long)N_NODES * 128 / 4) return;
    float4 v = ((const float4*)x)[i];
    ushort4 o;
    o.x = f2bf(v.x); o.y = f2bf(v.y); o.z = f2bf(v.z); o.w = f2bf(v.w);
    ((ushort4*)xb)[i] = o;
}

// Wt[m][k] = bf16(W[k][m])
__global__ void cvt_w_kernel(const float* __restrict__ W, unsigned short* __restrict__ Wt,
                             int K, int M) {
    int i = blockIdx.x * blockDim.x + threadIdx.x;
    if (i >= K * M) return;
    int k = i / M, m = i % M;
    Wt[(long)m * K + k] = f2bf(W[i]);
}

// ---------------- CSR gather aggregation (bf16 in, bf16/f32 out) ----------------
// one 64-lane wave per dst node; lane owns C/64 channels
template<int C, bool BIAS, bool RELU, bool LOGSM, bool OUTF32>
__global__ void agg_csr_kernel(const unsigned short* __restrict__ h,
                               const float* __restrict__ dinv,
                               const int* __restrict__ rowptr, const int* __restrict__ deg,
                               const int2* __restrict__ sedge,
                               const float* __restrict__ bias, void* __restrict__ outv) {
    constexpr int V = C / 64;  // 2 for C=128, 1 for C=64
    int gw = (int)((blockIdx.x * (long)blockDim.x + threadIdx.x) >> 6);
    int lane = threadIdx.x & 63;
    if (gw >= N_NODES) return;

    float di = dinv[gw];
    int st = rowptr[gw];
    int cnt = deg[gw];
    float a0, a1 = 0.0f;
    if constexpr (V == 2) {
        unsigned int u = ((const unsigned int*)(h + (long)gw * C))[lane];
        a0 = di * bflo2f(u); a1 = di * bfhi2f(u);
    } else {
        a0 = di * bflo2f(h[(long)gw * C + lane]);
    }

    int k = 0;
    for (; k + 4 <= cnt; k += 4) {
        int2 r0 = sedge[st + k],     r1 = sedge[st + k + 1];
        int2 r2 = sedge[st + k + 2], r3 = sedge[st + k + 3];
        float w0 = __int_as_float(r0.y), w1 = __int_as_float(r1.y);
        float w2 = __int_as_float(r2.y), w3 = __int_as_float(r3.y);
        if constexpr (V == 2) {
            unsigned int u0 = ((const unsigned int*)(h + (long)r0.x * C))[lane];
            unsigned int u1 = ((const unsigned int*)(h + (long)r1.x * C))[lane];
            unsigned int u2 = ((const unsigned int*)(h + (long)r2.x * C))[lane];
            unsigned int u3 = ((const unsigned int*)(h + (long)r3.x * C))[lane];
            a0 += w0 * bflo2f(u0); a1 += w0 * bfhi2f(u0);
            a0 += w1 * bflo2f(u1); a1 += w1 * bfhi2f(u1);
            a0 += w2 * bflo2f(u2); a1 += w2 * bfhi2f(u2);
            a0 += w3 * bflo2f(u3); a1 += w3 * bfhi2f(u3);
        } else {
            a0 += w0 * bflo2f(h[(long)r0.x * C + lane]);
            a0 += w1 * bflo2f(h[(long)r1.x * C + lane]);
            a0 += w2 * bflo2f(h[(long)r2.x * C + lane]);
            a0 += w3 * bflo2f(h[(long)r3.x * C + lane]);
        }
    }
    for (; k < cnt; ++k) {
        int2 r = sedge[st + k];
        float w = __int_as_float(r.y);
        if constexpr (V == 2) {
            unsigned int u = ((const unsigned int*)(h + (long)r.x * C))[lane];
            a0 += w * bflo2f(u); a1 += w * bfhi2f(u);
        } else {
            a0 += w * bflo2f(h[(long)r.x * C + lane]);
        }
    }

    a0 *= di; a1 *= di;
    if constexpr (BIAS) {
        if constexpr (V == 2) { a0 += bias[lane * 2]; a1 += bias[lane * 2 + 1]; }
        else a0 += bias[lane];
    }
    if constexpr (RELU) { a0 = fmaxf(a0, 0.0f); a1 = fmaxf(a1, 0.0f); }
    if constexpr (LOGSM) {  // V==1 only
        float m = a0;
#pragma unroll
        for (int o = 32; o > 0; o >>= 1) m = fmaxf(m, __shfl_xor(m, o));
        float e = expf(a0 - m), s = e;
#pragma unroll
        for (int o = 32; o > 0; o >>= 1) s += __shfl_xor(s, o);
        a0 = a0 - m - logf(s);
    }
    if constexpr (OUTF32) {
        float* out = (float*)outv;
        if constexpr (V == 2) {
            float2 r; r.x = a0; r.y = a1;
            *(float2*)(out + (long)gw * C + lane * 2) = r;
        } else {
            out[(long)gw * C + lane] = a0;
        }
    } else {
        unsigned short* out = (unsigned short*)outv;
        if constexpr (V == 2) {
            unsigned int up = (unsigned int)f2bf(a0) | ((unsigned int)f2bf(a1) << 16);
            ((unsigned int*)(out + (long)gw * C))[lane] = up;
        } else {
            out[(long)gw * C + lane] = f2bf(a0);
        }
    }
}

// ---------------- bf16 MFMA GEMM ----------------
// C[N,M](bf16) = A[N,K](bf16) @ Wt[M,K]^T (+bias)(relu)
// 64x64 block tile, 4 waves 2x2, each wave 32x32 via mfma_f32_16x16x32_bf16.
// Whole-K panels staged once to LDS with XOR row-swizzle (write & read identical).
template<int K, int M, bool BIAS, bool RELU>
__global__ __launch_bounds__(256) void gemm_mfma_kernel(
        const unsigned short* __restrict__ A,   // [NPAD][K]
        const unsigned short* __restrict__ Bt,  // [M][K]
        const float* __restrict__ bias,         // [M]
        unsigned short* __restrict__ Cb,        // [NPAD][M]
        int N) {
    constexpr int KC = K / 8;                    // 16B chunks per row
    __shared__ unsigned short As[64 * K];
    __shared__ unsigned short Bs[64 * K];

    int tid = threadIdx.x;
    int row0 = blockIdx.x * 64;
    int col0 = blockIdx.y * 64;

    const unsigned short* Ap = A + (long)row0 * K;
    const unsigned short* Bp = Bt + (long)col0 * K;

    // stage both panels; LDS byte = (c*16) ^ ((row&7)<<4)
    for (int c = tid; c < 64 * KC; c += 256) {
        int r = c / KC;
        unsigned int swz = ((unsigned int)c * 16u) ^ ((unsigned int)(r & 7) << 4);
        bf16x8 va = *(const bf16x8*)(Ap + c * 8);
        bf16x8 vb = *(const bf16x8*)(Bp + c * 8);
        *(bf16x8*)((char*)As + swz) = va;
        *(bf16x8*)((char*)Bs + swz) = vb;
    }
    __syncthreads();

    int lane = tid & 63;
    int wv = tid >> 6;
    int wr = wv >> 1, wc = wv & 1;      // wave tile origin (wr*32, wc*32)
    int lr = lane & 15;
    int kg = lane >> 4;                 // k-group: k = kg*8 + j

    f32x4 acc[2][2] = {};

    for (int k0 = 0; k0 < K; k0 += 32) {
        bf16x8 a[2], b[2];
#pragma unroll
        for (int mi = 0; mi < 2; ++mi) {
            int r = wr * 32 + mi * 16 + lr;
            unsigned int byteo = (unsigned int)((r * K + k0 + kg * 8) * 2);
            byteo ^= (unsigned int)((r & 7) << 4);
            a[mi] = *(const bf16x8*)((const char*)As + byteo);
        }
#pragma unroll
        for (int ni = 0; ni < 2; ++ni) {
            int r = wc * 32 + ni * 16 + lr;
            unsigned int byteo = (unsigned int)((r * K + k0 + kg * 8) * 2);
            byteo ^= (unsigned int)((r & 7) << 4);
            b[ni] = *(const bf16x8*)((const char*)Bs + byteo);
        }
#pragma unroll
        for (int mi = 0; mi < 2; ++mi)
#pragma unroll
            for (int ni = 0; ni < 2; ++ni)
                acc[mi][ni] = __builtin_amdgcn_mfma_f32_16x16x32_bf16(
                    a[mi], b[ni], acc[mi][ni], 0, 0, 0);
    }

    // epilogue: C/D layout col=lane&15, row=(lane>>4)*4+i
#pragma unroll
    for (int mi = 0; mi < 2; ++mi) {
#pragma unroll
        for (int ni = 0; ni < 2; ++ni) {
            int col = col0 + wc * 32 + ni * 16 + lr;
            float bv = BIAS ? bias[col] : 0.0f;
#pragma unroll
            for (int i = 0; i < 4; ++i) {
                int row = row0 + wr * 32 + mi * 16 + kg * 4 + i;
                if (row < N) {
                    float v = acc[mi][ni][i] + bv;
                    if (RELU) v = fmaxf(v, 0.0f);
                    Cb[(long)row * M + col] = f2bf(v);
                }
            }
        }
    }
}

// ---------------- launch ----------------

extern "C" void kernel_launch(void* const* d_in, const int* in_sizes, int n_in,
                              void* d_out, int out_size, void* d_ws, size_t ws_size,
                              hipStream_t stream) {
    const float* x  = (const float*)d_in[0];
    const int* edge = (const int*)d_in[1];
    const float* W1 = (const float*)d_in[2];
    const float* b1 = (const float*)d_in[3];
    const float* W2 = (const float*)d_in[4];
    const float* b2 = (const float*)d_in[5];
    const float* W3 = (const float*)d_in[6];
    const float* b3 = (const float*)d_in[7];
    float* out = (float*)d_out;

    const int* src = edge;
    const int* dst = edge + N_EDGES;

    // workspace: fp32/int CSR region, then bf16 buffers
    float* ws    = (float*)d_ws;
    float* dinv  = ws;                                   // N
    int*   degi  = (int*)(ws + 100000);
    int*   rowp  = (int*)(ws + 200000);
    int*   curs  = (int*)(ws + 300000);
    int*   bsum  = (int*)(ws + 400000);
    int2*  sedge = (int2*)(ws + 401024);                 // E * 8B (8B-aligned)
    unsigned short* P1  = (unsigned short*)(ws + 3601024);   // [NPAD][128]
    unsigned short* P2  = P1 + (size_t)NPAD * 128;           // [NPAD][128]
    unsigned short* P3  = P2 + (size_t)NPAD * 128;           // [NPAD][256]
    unsigned short* Wt1 = P3 + (size_t)NPAD * 256;           // [256][128]
    unsigned short* Wt2 = Wt1 + 128 * 256;                   // [128][256]
    unsigned short* Wt3 = Wt2 + 256 * 128;                   // [64][128]

    const int BT = 256;
    int gN = (N_NODES + BT - 1) / BT;
    int gE = (N_EDGES + BT - 1) / BT;
    int gAgg = (int)(((long)N_NODES * 64 + BT - 1) / BT);
    int gRows = (N_NODES + 63) / 64;   // 1563

    // --- degree + dinv + CSR ---
    hipMemsetAsync(degi, 0, N_NODES * sizeof(int), stream);
    deg_count_kernel<<<gE, BT, 0, stream>>>(dst, degi);
    dinv_kernel<<<gN, BT, 0, stream>>>(degi, dinv);
    scan1_kernel<<<NBLK_SCAN, 256, 0, stream>>>(degi, rowp, bsum);
    scan2_kernel<<<1, 512, 0, stream>>>(bsum);
    scan3_kernel<<<NBLK_SCAN, 256, 0, stream>>>(rowp, bsum);
    copy_rowp_kernel<<<NBLK_SCAN, 256, 0, stream>>>(rowp, curs);
    scatter_kernel<<<gE, BT, 0, stream>>>(src, dst, dinv, curs, sedge);

    // --- conversions ---
    cvt_x_kernel<<<(int)(((long)N_NODES * 128 / 4 + BT - 1) / BT), BT, 0, stream>>>(x, P1);
    cvt_w_kernel<<<(128 * 256 + BT - 1) / BT, BT, 0, stream>>>(W1, Wt1, 128, 256);
    cvt_w_kernel<<<(256 * 128 + BT - 1) / BT, BT, 0, stream>>>(W2, Wt2, 256, 128);
    cvt_w_kernel<<<(128 * 64 + BT - 1) / BT, BT, 0, stream>>>(W3, Wt3, 128, 64);

    // --- layer 1: agg(x) [P1->P2], gemm 128->256 +b1 +relu [P2->P3] ---
    agg_csr_kernel<128, false, false, false, false><<<gAgg, BT, 0, stream>>>(
        P1, dinv, rowp, degi, sedge, nullptr, P2);
    {
        dim3 g(gRows, 4);
        gemm_mfma_kernel<128, 256, true, true><<<g, BT, 0, stream>>>(P2, Wt1, b1, P3, N_NODES);
    }

    // --- layer 2: gemm 256->128 [P3->P1], agg +b2 +relu [P1->P2] ---
    {
        dim3 g(gRows, 2);
        gemm_mfma_kernel<256, 128, false, false><<<g, BT, 0, stream>>>(P3, Wt2, nullptr, P1, N_NODES);
    }
    agg_csr_kernel<128, true, true, false, false><<<gAgg, BT, 0, stream>>>(
        P1, dinv, rowp, degi, sedge, b2, P2);

    // --- layer 3: gemm 128->64 [P2->P1], agg +b3 +relu +logsm [P1->out] ---
    {
        dim3 g(gRows, 1);
        gemm_mfma_kernel<128, 64, false, false><<<g, BT, 0, stream>>>(P2, Wt3, nullptr, P1, N_NODES);
    }
    agg_csr_kernel<64, true, true, true, true><<<gAgg, BT, 0, stream>>>(
        P1, dinv, rowp, degi, sedge, b3, out);

    (void)in_sizes; (void)n_in; (void)out_size; (void)ws_size;
}